// Round 13
// baseline (165.475 us; speedup 1.0000x reference)
//
#include <hip/hip_runtime.h>
#include <math.h>

typedef __attribute__((ext_vector_type(2))) _Float16 f16x2;
typedef __attribute__((ext_vector_type(4))) _Float16 f16x4;
typedef __attribute__((ext_vector_type(8))) _Float16 f16x8;
typedef __attribute__((ext_vector_type(4))) float f32x4;

#if __has_builtin(__builtin_amdgcn_fdot2)
#define FDOT2(a, b, c) __builtin_amdgcn_fdot2((a), (b), (c), false)
#else
static __device__ __forceinline__ float FDOT2(f16x2 a, f16x2 b, float c) {
  return c + (float)a[0] * (float)b[0] + (float)a[1] * (float)b[1];
}
#endif

// Workspace byte offsets
#define XPAD8_B  0           // [2][16 gg][68 y][72 x][8 ci] f16 (data at y+2,x+2)
#define WFC_B    2506752     // convw B-frags [25 t][4 cc][4 ntg][64 l] f16x8
#define WFE_B    2916352     // enc  B-frags [9 t][2 cc][7 nt][64 l] f16x8
#define WFEATP_B 3045376     // [2][8 gg][66][68][8] f16 pre-edge W (data at +1,+1)
#define WEDGET_B 4194304     // [9 k][8 gg] f16x8 (j fastest) depthwise weights
#define BCOMB_B  4195456     // [64] f32
#define AVG_B    4195712     // [128] f32 (seeded with bias)
#define BAR_B    4196224     // [2] u32 grid-barrier (memset 0 each launch)

// Sense-reversing grid barrier; all 512 blocks resident (2/CU by LDS).
static __device__ __forceinline__ void grid_barrier(unsigned int* bar, unsigned int nb) {
  __syncthreads();
  if (threadIdx.x == 0) {
    __threadfence();
    unsigned int g = atomicAdd(bar + 1, 0u);
    if (atomicAdd(bar, 1u) == nb - 1) {
      atomicExch(bar, 0u);
      __threadfence();
      atomicAdd(bar + 1, 1u);
    } else {
      while (atomicAdd(bar + 1, 0u) == g) __builtin_amdgcn_s_sleep(8);
      __threadfence();
    }
  }
  __syncthreads();
}

// Phase-2 (enccarafe) shared overlays — R10 layout, 37920 B
#define SM_XT  0       // 16*624 f16 = 19968 B  [gg][6r][13c][8]
#define SM_XSV 19968   // 8*328 f16 = 5248 B    [gg][4r][10c][8]
#define SM_TS  25216   // 8*584 f16 = 9344 B    [gg][6r][12c][8] (alias sml)
#define SM_SML 25216   // 16*116 f32 = 7424 B
#define SM_SMW 32640   // 15*16*4 f16x2 = 3840 B
#define SM_WED 36480   // 72 f16x8 = 1152 B
#define SM_TLA 37632   // 8 f32
#define SM_GSH 37664   // 64 f32
// Phase-1 (convw): xs0@0 (24832), xs1@24832 (24832), red@49664 (2x2048), redm@53760 (2x128)
#define SMEM_BYTES 54272

__global__ __launch_bounds__(512, 4) void fused_kernel(
    const float* __restrict__ X, const float* __restrict__ w3,
    const float* __restrict__ b3, const float* __restrict__ w5,
    const float* __restrict__ b5, const float* __restrict__ wa1,
    const float* __restrict__ ba1, const float* __restrict__ wa2,
    const float* __restrict__ ba2, const float* __restrict__ wedge,
    const float* __restrict__ wenc, char* __restrict__ wsb,
    float* __restrict__ out) {
  __shared__ __attribute__((aligned(16))) char SMEM[SMEM_BYTES];
  const int tid = threadIdx.x;
  const int bid = blockIdx.x;  // 0..511
  unsigned int* bar = (unsigned int*)(wsb + BAR_B);

  // ===================== Phase 0: prep (one pass, 262144 threads) ==========
  {
    const int idx = bid * 512 + tid;
    if (idx < 156672) {  // Xpad8
      int x = idx % 72;
      int t = idx / 72;
      int y = t % 68;
      int t2 = t / 68;
      int gg = t2 & 15, b = t2 >> 4;
      int yy = y - 2, xx = x - 2;
      bool ok = (yy >= 0 && yy < 64 && xx >= 0 && xx < 64);
      f16x8 h;
#pragma unroll
      for (int j = 0; j < 8; ++j) {
        float v = ok ? X[((b * 128 + gg * 8 + j) << 12) + yy * 64 + xx] : 0.f;
        h[j] = (_Float16)v;
      }
      ((f16x8*)(wsb + XPAD8_B))[idx] = h;
    }
    if (idx < 25600) {  // convw frags: ((t*4+cc)*4+ntg)*64 + l
      int l = idx & 63;
      int q = idx >> 6;
      int ntg = q & 3;
      int q2 = q >> 2;
      int cc = q2 & 3;
      int t = q2 >> 2;
      int ky = t / 5, kx = t % 5;
      int oc = ntg * 16 + (l & 15);
      int ci0 = cc * 32 + (l >> 4) * 8;
      f16x8 h;
#pragma unroll
      for (int i = 0; i < 8; ++i) {
        int ci = ci0 + i;
        float v = w5[(oc * 128 + ci) * 25 + t];
        if (ky >= 1 && ky <= 3 && kx >= 1 && kx <= 3)
          v += w3[(oc * 128 + ci) * 9 + (ky - 1) * 3 + (kx - 1)];
        h[i] = (_Float16)v;
      }
      ((f16x8*)(wsb + WFC_B))[idx] = h;
    }
    if (idx < 8064) {  // enc frags: ((t*2+cc)*7+nt)*64 + l
      int l = idx & 63;
      int q = idx >> 6;
      int nt = q % 7;
      int q2 = q / 7;
      int cc = q2 & 1;
      int t = q2 >> 1;
      int oc = nt * 16 + (l & 15);
      int ci0 = cc * 32 + (l >> 4) * 8;
      f16x8 h;
#pragma unroll
      for (int i = 0; i < 8; ++i) {
        float v = (oc < 100) ? wenc[(oc * 64 + ci0 + i) * 9 + t] : 0.f;
        h[i] = (_Float16)v;
      }
      ((f16x8*)(wsb + WFE_B))[idx] = h;
    }
    if (idx < 6272) {  // wfeatp border zeros
      int plane = idx / 392, p = idx % 392;
      int r, c;
      if (p < 136) {
        r = (p >= 68) ? 65 : 0;
        c = p % 68;
      } else {
        int q = p - 136;
        r = 1 + (q >> 2);
        int cm = q & 3;
        c = (cm == 0) ? 0 : (64 + cm);
      }
      f16x8 z = {(_Float16)0.f, (_Float16)0.f, (_Float16)0.f, (_Float16)0.f,
                 (_Float16)0.f, (_Float16)0.f, (_Float16)0.f, (_Float16)0.f};
      *(f16x8*)((_Float16*)(wsb + WFEATP_B) + ((size_t)(plane * 66 + r) * 68 + c) * 8) = z;
    }
    if (idx < 72) {  // wedgeT
      int k = idx >> 3, gg = idx & 7;
      f16x8 h;
#pragma unroll
      for (int j = 0; j < 8; ++j) h[j] = (_Float16)wedge[(gg * 8 + j) * 9 + k];
      ((f16x8*)(wsb + WEDGET_B))[idx] = h;
    }
    if (idx < 64) ((float*)(wsb + BCOMB_B))[idx] = b3[idx] + b5[idx];
    if (idx < 128) ((float*)(wsb + AVG_B))[idx] = b3[idx & 63] + b5[idx & 63];
  }
  grid_barrier(bar, 512);

  // ===================== Phase 1: convw (two parallel 256-thr units) =======
  {
    const _Float16* xpad8 = (const _Float16*)(wsb + XPAD8_B);
    const f16x8* wfc = (const f16x8*)(wsb + WFC_B);
    const float* bcomb = (const float*)(wsb + BCOMB_B);
    _Float16* wfeatp = (_Float16*)(wsb + WFEATP_B);
    float* avg = (float*)(wsb + AVG_B);

    const int half = tid >> 8;
    const int t2 = tid & 255;
    const int u = bid * 2 + half;  // 0..1023 == R10 grid (8,16,8)
    const int bx = u & 7, by = (u >> 3) & 15, zz = u >> 7;
    const int b = zz >> 2, ntg = zz & 3;
    const int tx0 = bx * 8, ty0 = by * 4;
    _Float16* xs = (_Float16*)(SMEM + half * 24832);            // [16][776]
    float* red = (float*)(SMEM + 49664 + half * 2048);          // [2][64][4]
    float* redm = (float*)(SMEM + 53760 + half * 128);          // [2][16]

    for (int uu = t2; uu < 1536; uu += 256) {
      int gg = uu / 96;
      int rem = uu - gg * 96;
      int r = rem / 12, c = rem - r * 12;
      f16x8 v = *(const f16x8*)&xpad8[((size_t)((b * 16 + gg) * 68 + ty0 + r) * 72 + tx0 + c) * 8];
      *(f16x8*)&xs[gg * 776 + r * 96 + c * 8] = v;
    }
    __syncthreads();

    const int w = __builtin_amdgcn_readfirstlane(t2 >> 6);
    const int l = t2 & 63;
    const int pg = w & 1, kh = w >> 1;
    const int lm = l & 15, lg = l >> 4;
    const int p = pg * 16 + lm;
    const int abase = (p >> 3) * 96 + (p & 7) * 8;

    f32x4 acc = {0.f, 0.f, 0.f, 0.f};
    for (int dy = 0; dy < 5; ++dy) {
      for (int dx = 0; dx < 5; ++dx) {
        const int t = dy * 5 + dx;
        const int toff = abase + dy * 96 + dx * 8;
#pragma unroll
        for (int cc2 = 0; cc2 < 2; ++cc2) {
          const int cc = kh * 2 + cc2;
          f16x8 a = *(const f16x8*)&xs[(cc * 4 + lg) * 776 + toff];
          f16x8 bb = wfc[((t * 4 + cc) * 4 + ntg) * 64 + l];
          acc = __builtin_amdgcn_mfma_f32_16x16x32_f16(a, bb, acc, 0, 0, 0);
        }
      }
    }

    if (kh == 1) {
#pragma unroll
      for (int r = 0; r < 4; ++r) red[(pg * 64 + l) * 4 + r] = acc[r];
    }
    __syncthreads();
    if (kh == 0) {
#pragma unroll
      for (int r = 0; r < 4; ++r) acc[r] += red[(pg * 64 + l) * 4 + r];
      float s = acc[0] + acc[1] + acc[2] + acc[3];
      s += __shfl_xor(s, 16);
      s += __shfl_xor(s, 32);
      if (lg == 0) redm[pg * 16 + lm] = s;
      const float bias = bcomb[ntg * 16 + lm];
#pragma unroll
      for (int r = 0; r < 4; ++r) {
        int pd = pg * 16 + lg * 4 + r;
        xs[pd * 24 + lm] = (_Float16)(acc[r] + bias);
      }
    }
    __syncthreads();
    if (t2 < 64) {
      int pd = t2 >> 1, g2 = t2 & 1;
      f16x8 v = *(const f16x8*)&xs[pd * 24 + g2 * 8];
      int gy = ty0 + (pd >> 3), gx = tx0 + (pd & 7);
      *(f16x8*)&wfeatp[((size_t)((b * 8 + ntg * 2 + g2) * 66 + 1 + gy) * 68 + 1 + gx) * 8] = v;
    }
    if (t2 < 16) {
      float tot = redm[t2] + redm[16 + t2];
      atomicAdd(&avg[b * 64 + ntg * 16 + t2], tot * (1.f / 4096.f));
    }
  }
  grid_barrier(bar, 512);

  // ===================== Phase 2: enccarafe (R10 body, 512 thr) ============
  {
    const _Float16* wfeatp = (const _Float16*)(wsb + WFEATP_B);
    const f16x8* wfe = (const f16x8*)(wsb + WFE_B);
    const _Float16* xpad8 = (const _Float16*)(wsb + XPAD8_B);
    const f16x8* wedgeT = (const f16x8*)(wsb + WEDGET_B);
    const float* avg = (const float*)(wsb + AVG_B);

    _Float16* xt = (_Float16*)(SMEM + SM_XT);
    _Float16* xsv = (_Float16*)(SMEM + SM_XSV);
    _Float16* ts = (_Float16*)(SMEM + SM_TS);
    float* sml = (float*)(SMEM + SM_SML);
    f16x2* smw2 = (f16x2*)(SMEM + SM_SMW);
    f16x8* wedt = (f16x8*)(SMEM + SM_WED);
    float* tlat = (float*)(SMEM + SM_TLA);
    float* gsh = (float*)(SMEM + SM_GSH);

    const int bx = bid & 7, by = (bid >> 3) & 31, b = bid >> 8;
    const int tx0 = bx * 8, ty0 = by * 2;

    for (int u = tid; u < 1248; u += 512) {
      int gg = u / 78;
      int rem = u - gg * 78;
      int r = rem / 13, c = rem - r * 13;
      f16x8 v = *(const f16x8*)&xpad8[((size_t)((b * 16 + gg) * 68 + ty0 + r) * 72 + tx0 + c) * 8];
      *(f16x8*)&xt[gg * 624 + r * 104 + c * 8] = v;
    }
    for (int u = tid; u < 576; u += 512) {
      int gg = u / 72;
      int rem = u - gg * 72;
      int r = rem / 12, c = rem - r * 12;
      int pr = ty0 - 1 + r, pc = tx0 - 1 + c;
      f16x8 v = {(_Float16)0.f, (_Float16)0.f, (_Float16)0.f, (_Float16)0.f,
                 (_Float16)0.f, (_Float16)0.f, (_Float16)0.f, (_Float16)0.f};
      if (pr >= 0 && pr < 66 && pc >= 0 && pc < 68)
        v = *(const f16x8*)&wfeatp[((size_t)((b * 8 + gg) * 66 + pr) * 68 + pc) * 8];
      *(f16x8*)&ts[gg * 584 + r * 96 + c * 8] = v;
    }
    if (tid < 72) wedt[tid] = wedgeT[tid];
    if (tid < 8) {
      float s = ba1[tid];
      for (int i = 0; i < 64; ++i) s += wa1[tid * 64 + i] * avg[b * 64 + i];
      tlat[tid] = s;
    }
    __syncthreads();
    if (tid < 64) {
      float s = ba2[tid];
#pragma unroll
      for (int j = 0; j < 8; ++j) s += wa2[tid * 8 + j] * tlat[j];
      gsh[tid] = 1.f / (1.f + expf(-s));
    }
    __syncthreads();

    // edge -> xsv (8gg x 4r x 10c)
    if (tid < 320) {
      int gg = tid / 40;
      int rem = tid - gg * 40;
      int r6 = rem / 10, c10 = rem - r6 * 10;
      int vy = ty0 - 1 + r6, vx = tx0 - 1 + c10;
      f16x8 res = {(_Float16)0.f, (_Float16)0.f, (_Float16)0.f, (_Float16)0.f,
                   (_Float16)0.f, (_Float16)0.f, (_Float16)0.f, (_Float16)0.f};
      if (vy >= 0 && vy < 64 && vx >= 0 && vx < 64) {
        float vout[8];
        f16x8 ctr = *(const f16x8*)&ts[gg * 584 + (r6 + 1) * 96 + (c10 + 1) * 8];
#pragma unroll
        for (int j = 0; j < 8; ++j) vout[j] = (float)ctr[j] * gsh[gg * 8 + j];
#pragma unroll
        for (int ky = 0; ky < 3; ++ky) {
#pragma unroll
          for (int kx = 0; kx < 3; ++kx) {
            int k = ky * 3 + kx;
            f16x8 tv = *(const f16x8*)&ts[gg * 584 + (r6 + ky) * 96 + (c10 + kx) * 8];
            f16x8 wv = wedt[k * 8 + gg];
#pragma unroll
            for (int j = 0; j < 8; ++j) vout[j] = fmaf((float)wv[j], (float)tv[j], vout[j]);
          }
        }
#pragma unroll
        for (int j = 0; j < 8; ++j) res[j] = (_Float16)vout[j];
      }
      *(f16x8*)&xsv[gg * 328 + r6 * 80 + c10 * 8] = res;
    }
    __syncthreads();

    // enc MFMA -> sml (7 waves x 1 nt)
    {
      const int w = __builtin_amdgcn_readfirstlane(tid >> 6);
      const int l = tid & 63;
      if (w < 7) {
        const int nt = w;
        const int lm = l & 15, lg = l >> 4;
        const int abase = (lm >> 3) * 80 + (lm & 7) * 8;

        f32x4 a0 = {0.f, 0.f, 0.f, 0.f};
        for (int dy = 0; dy < 3; ++dy) {
          for (int dx = 0; dx < 3; ++dx) {
            const int t = dy * 3 + dx;
            const int toff = abase + dy * 80 + dx * 8;
#pragma unroll
            for (int cc = 0; cc < 2; ++cc) {
              f16x8 a = *(const f16x8*)&xsv[(cc * 4 + lg) * 328 + toff];
              f16x8 b0 = wfe[((t * 2 + cc) * 7 + nt) * 64 + l];
              a0 = __builtin_amdgcn_mfma_f32_16x16x32_f16(a, b0, a0, 0, 0, 0);
            }
          }
        }
#pragma unroll
        for (int r = 0; r < 4; ++r)
          sml[(4 * lg + r) * 116 + nt * 16 + lm] = a0[r];
      }
    }
    __syncthreads();

    // softmax -> paired f16x2 weights
    if (tid < 64) {
      int pix = tid >> 2, sub = tid & 3;
      float lv[25];
      float m = -1e30f;
#pragma unroll
      for (int k = 0; k < 25; ++k) {
        lv[k] = sml[pix * 116 + k * 4 + sub];
        m = fmaxf(m, lv[k]);
      }
      float s = 0.f;
#pragma unroll
      for (int k = 0; k < 25; ++k) {
        lv[k] = __expf(lv[k] - m);
        s += lv[k];
      }
      float inv = 1.f / s;
#pragma unroll
      for (int ki = 0; ki < 5; ++ki) {
#pragma unroll
        for (int pr = 0; pr < 3; ++pr) {
          float wlo = lv[ki * 5 + 2 * pr] * inv;
          float whi = (2 * pr + 1 < 5) ? lv[ki * 5 + 2 * pr + 1] * inv : 0.f;
          f16x2 pk = {(_Float16)wlo, (_Float16)whi};
          smw2[((ki * 3 + pr) * 16 + pix) * 4 + sub] = pk;
        }
      }
    }
    __syncthreads();

    // carafe gather via fdot2: 512 thr = 16 slot(8ch) x 2 sy x 16 pix
    {
      const int slot = tid >> 5;
      const int rem = tid & 31;
      const int syh = rem >> 4, pix = rem & 15;
      const int py = pix >> 3, px = pix & 7;
      const _Float16* xb = xt + slot * 624;

      float acc[2][8];
#pragma unroll
      for (int s = 0; s < 2; ++s)
#pragma unroll
        for (int j = 0; j < 8; ++j) acc[s][j] = 0.f;

      union U8 { f16x8 v; unsigned int u[4]; };
#pragma unroll
      for (int ki = 0; ki < 5; ++ki) {
        const _Float16* row = xb + (py + ki) * 104 + px * 8;
        U8 C[6];
#pragma unroll
        for (int c = 0; c < 6; ++c) C[c].v = *(const f16x8*)(row + c * 8);
#pragma unroll
        for (int pr = 0; pr < 3; ++pr) {
          const f16x2* wp = &smw2[((ki * 3 + pr) * 16 + pix) * 4 + syh * 2];
          f16x2 w0 = wp[0], w1 = wp[1];
          const U8& A = C[2 * pr];
          const U8& B = C[2 * pr + 1];
#pragma unroll
          for (int k = 0; k < 4; ++k) {
            unsigned int lo = __builtin_amdgcn_perm(B.u[k], A.u[k], 0x05040100u);
            unsigned int hi = __builtin_amdgcn_perm(B.u[k], A.u[k], 0x07060302u);
            f16x2 xlo = __builtin_bit_cast(f16x2, lo);
            f16x2 xhi = __builtin_bit_cast(f16x2, hi);
            acc[0][2 * k] = FDOT2(w0, xlo, acc[0][2 * k]);
            acc[1][2 * k] = FDOT2(w1, xlo, acc[1][2 * k]);
            acc[0][2 * k + 1] = FDOT2(w0, xhi, acc[0][2 * k + 1]);
            acc[1][2 * k + 1] = FDOT2(w1, xhi, acc[1][2 * k + 1]);
          }
        }
      }
      int y0o = 2 * (ty0 + py) + syh, x0o = 2 * (tx0 + px);
#pragma unroll
      for (int j = 0; j < 8; ++j) {
        int c = slot * 8 + j;
        float* op = out + ((size_t)(b * 128 + c) * 128 + y0o) * 128 + x0o;
        float2 v0 = {acc[0][j], acc[1][j]};
        *(float2*)op = v0;
      }
    }
  }
}

// ---------------------------------------------------------------------------
extern "C" void kernel_launch(void* const* d_in, const int* in_sizes, int n_in,
                              void* d_out, int out_size, void* d_ws, size_t ws_size,
                              hipStream_t stream) {
  const float* X     = (const float*)d_in[0];
  const float* w3    = (const float*)d_in[1];
  const float* b3    = (const float*)d_in[2];
  const float* w5    = (const float*)d_in[3];
  const float* b5    = (const float*)d_in[4];
  const float* wa1   = (const float*)d_in[5];
  const float* ba1   = (const float*)d_in[6];
  const float* wa2   = (const float*)d_in[7];
  const float* ba2   = (const float*)d_in[8];
  const float* wedge = (const float*)d_in[9];
  const float* wenc  = (const float*)d_in[10];
  char* wsb = (char*)d_ws;  // ~4.2 MB
  float* out = (float*)d_out;

  hipMemsetAsync(wsb + BAR_B, 0, 8, stream);
  fused_kernel<<<512, 512, 0, stream>>>(X, w3, b3, w5, b5, wa1, ba1, wa2, ba2,
                                        wedge, wenc, wsb, out);
}

// Round 14
// 41.205 us; speedup vs baseline: 4.0158x; 4.0158x over previous
//
#include <hip/hip_runtime.h>
#include <math.h>

typedef __attribute__((ext_vector_type(2))) _Float16 f16x2;
typedef __attribute__((ext_vector_type(4))) _Float16 f16x4;
typedef __attribute__((ext_vector_type(8))) _Float16 f16x8;
typedef __attribute__((ext_vector_type(4))) float f32x4;

#if __has_builtin(__builtin_amdgcn_fdot2)
#define FDOT2(a, b, c) __builtin_amdgcn_fdot2((a), (b), (c), false)
#else
static __device__ __forceinline__ float FDOT2(f16x2 a, f16x2 b, float c) {
  return c + (float)a[0] * (float)b[0] + (float)a[1] * (float)b[1];
}
#endif

// Workspace byte offsets
#define XPAD8_B  0           // [2][16 gg][68 y][72 x][8 ci] f16 (data at y+2,x+2)
#define WFC_B    2506752     // convw B-frags [25 t][4 cc][4 ntg][64 l] f16x8
#define WFE_B    2916352     // enc  B-frags [9 t][2 cc][7 nt][64 l] f16x8
#define WFEATP_B 3045376     // [2][8 gg][66][68][8] f16 pre-edge W (data at +1,+1)
#define WEDGET_B 4194304     // [9 k][8 gg] f16x8 (j fastest) depthwise weights
#define BCOMB_B  4195456     // [64] f32
#define AVG_B    4195712     // [128] f32 (seeded with bias)
// total ~4.2 MB

// ---------------------------------------------------------------------------
// prep: Xpad8, MFMA B-frag packs (K=32), wfeatp border zeros, wedgeT, bias.
// ---------------------------------------------------------------------------
__global__ __launch_bounds__(256) void prep_kernel(
    const float* __restrict__ X,
    const float* __restrict__ w3, const float* __restrict__ b3,
    const float* __restrict__ w5, const float* __restrict__ b5,
    const float* __restrict__ wedge, const float* __restrict__ wenc,
    char* __restrict__ wsb) {
  int idx = blockIdx.x * 256 + threadIdx.x;
  if (idx < 156672) {  // Xpad8
    int x = idx % 72;
    int t = idx / 72;
    int y = t % 68;
    int t2 = t / 68;
    int gg = t2 & 15, b = t2 >> 4;
    int yy = y - 2, xx = x - 2;
    bool ok = (yy >= 0 && yy < 64 && xx >= 0 && xx < 64);
    f16x8 h;
#pragma unroll
    for (int j = 0; j < 8; ++j) {
      float v = ok ? X[((b * 128 + gg * 8 + j) << 12) + yy * 64 + xx] : 0.f;
      h[j] = (_Float16)v;
    }
    ((f16x8*)(wsb + XPAD8_B))[idx] = h;
  }
  if (idx < 25600) {  // convw frags: ((t*4+cc)*4+ntg)*64 + l
    int l = idx & 63;
    int q = idx >> 6;
    int ntg = q & 3;
    int q2 = q >> 2;
    int cc = q2 & 3;
    int t = q2 >> 2;
    int ky = t / 5, kx = t % 5;
    int oc = ntg * 16 + (l & 15);
    int ci0 = cc * 32 + (l >> 4) * 8;
    f16x8 h;
#pragma unroll
    for (int i = 0; i < 8; ++i) {
      int ci = ci0 + i;
      float v = w5[(oc * 128 + ci) * 25 + t];
      if (ky >= 1 && ky <= 3 && kx >= 1 && kx <= 3)
        v += w3[(oc * 128 + ci) * 9 + (ky - 1) * 3 + (kx - 1)];
      h[i] = (_Float16)v;
    }
    ((f16x8*)(wsb + WFC_B))[idx] = h;
  }
  if (idx < 8064) {  // enc frags: ((t*2+cc)*7+nt)*64 + l
    int l = idx & 63;
    int q = idx >> 6;
    int nt = q % 7;
    int q2 = q / 7;
    int cc = q2 & 1;
    int t = q2 >> 1;
    int oc = nt * 16 + (l & 15);
    int ci0 = cc * 32 + (l >> 4) * 8;
    f16x8 h;
#pragma unroll
    for (int i = 0; i < 8; ++i) {
      float v = (oc < 100) ? wenc[(oc * 64 + ci0 + i) * 9 + t] : 0.f;
      h[i] = (_Float16)v;
    }
    ((f16x8*)(wsb + WFE_B))[idx] = h;
  }
  if (idx < 6272) {  // wfeatp border zeros: 16 planes x 392 positions
    int plane = idx / 392, p = idx % 392;
    int r, c;
    if (p < 136) {
      r = (p >= 68) ? 65 : 0;
      c = p % 68;
    } else {
      int q = p - 136;
      r = 1 + (q >> 2);
      int cm = q & 3;
      c = (cm == 0) ? 0 : (64 + cm);
    }
    f16x8 z = {(_Float16)0.f, (_Float16)0.f, (_Float16)0.f, (_Float16)0.f,
               (_Float16)0.f, (_Float16)0.f, (_Float16)0.f, (_Float16)0.f};
    *(f16x8*)((_Float16*)(wsb + WFEATP_B) + ((size_t)(plane * 66 + r) * 68 + c) * 8) = z;
  }
  if (idx < 72) {  // wedgeT [k][gg] f16x8 over j
    int k = idx >> 3, gg = idx & 7;
    f16x8 h;
#pragma unroll
    for (int j = 0; j < 8; ++j) h[j] = (_Float16)wedge[(gg * 8 + j) * 9 + k];
    ((f16x8*)(wsb + WEDGET_B))[idx] = h;
  }
  if (idx < 64) ((float*)(wsb + BCOMB_B))[idx] = b3[idx] + b5[idx];
  if (idx < 128) ((float*)(wsb + AVG_B))[idx] = b3[idx & 63] + b5[idx & 63];
}

// ---------------------------------------------------------------------------
// convw: 5x5 conv, mfma 16x16x32, fused mean. Tile 8x4 px, 16 oc.
// Grid (8,16,8): z = b*4 + ntg -> 1024 blocks = 4 blocks/CU, 16 waves/CU.
// 256 thr = 4 waves: (pg = w&1 pixel 16-group, kh = w>>1 K-half).
// R14: 2 independent MFMA chains per wave (cc2 parity) to halve chain depth.
// ---------------------------------------------------------------------------
__global__ __launch_bounds__(256) void convw_kernel(
    const _Float16* __restrict__ xpad8, const f16x8* __restrict__ wfc,
    const float* __restrict__ bcomb, _Float16* __restrict__ wfeatp,
    float* __restrict__ avg) {
  __shared__ __attribute__((aligned(16))) _Float16 xs[16 * 776];
  __shared__ float red[2][64][4];
  __shared__ float redm[2][16];
  const int tid = threadIdx.x;
  const int z = blockIdx.z;
  const int b = z >> 2, ntg = z & 3;
  const int tx0 = blockIdx.x * 8, ty0 = blockIdx.y * 4;

  for (int u = tid; u < 1536; u += 256) {
    int gg = u / 96;
    int rem = u - gg * 96;
    int r = rem / 12, c = rem - r * 12;
    f16x8 v = *(const f16x8*)&xpad8[((size_t)((b * 16 + gg) * 68 + ty0 + r) * 72 + tx0 + c) * 8];
    *(f16x8*)&xs[gg * 776 + r * 96 + c * 8] = v;
  }
  __syncthreads();

  const int w = __builtin_amdgcn_readfirstlane(tid >> 6);
  const int l = tid & 63;
  const int pg = w & 1, kh = w >> 1;
  const int lm = l & 15, lg = l >> 4;
  const int p = pg * 16 + lm;
  const int abase = (p >> 3) * 96 + (p & 7) * 8;

  f32x4 acc0 = {0.f, 0.f, 0.f, 0.f}, acc1 = {0.f, 0.f, 0.f, 0.f};
  for (int dy = 0; dy < 5; ++dy) {
    for (int dx = 0; dx < 5; ++dx) {
      const int t = dy * 5 + dx;
      const int toff = abase + dy * 96 + dx * 8;
      {
        const int cc = kh * 2;
        f16x8 a = *(const f16x8*)&xs[(cc * 4 + lg) * 776 + toff];
        f16x8 bb = wfc[((t * 4 + cc) * 4 + ntg) * 64 + l];
        acc0 = __builtin_amdgcn_mfma_f32_16x16x32_f16(a, bb, acc0, 0, 0, 0);
      }
      {
        const int cc = kh * 2 + 1;
        f16x8 a = *(const f16x8*)&xs[(cc * 4 + lg) * 776 + toff];
        f16x8 bb = wfc[((t * 4 + cc) * 4 + ntg) * 64 + l];
        acc1 = __builtin_amdgcn_mfma_f32_16x16x32_f16(a, bb, acc1, 0, 0, 0);
      }
    }
  }
  f32x4 acc = acc0 + acc1;

  if (kh == 1) {
#pragma unroll
    for (int r = 0; r < 4; ++r) red[pg][l][r] = acc[r];
  }
  __syncthreads();
  if (kh == 0) {
#pragma unroll
    for (int r = 0; r < 4; ++r) acc[r] += red[pg][l][r];
    float s = acc[0] + acc[1] + acc[2] + acc[3];
    s += __shfl_xor(s, 16);
    s += __shfl_xor(s, 32);
    if (lg == 0) redm[pg][lm] = s;
    const float bias = bcomb[ntg * 16 + lm];
#pragma unroll
    for (int r = 0; r < 4; ++r) {
      int pd = pg * 16 + lg * 4 + r;
      xs[pd * 24 + lm] = (_Float16)(acc[r] + bias);
    }
  }
  __syncthreads();
  if (tid < 64) {
    int pd = tid >> 1, g2 = tid & 1;
    f16x8 v = *(const f16x8*)&xs[pd * 24 + g2 * 8];
    int gy = ty0 + (pd >> 3), gx = tx0 + (pd & 7);
    *(f16x8*)&wfeatp[((size_t)((b * 8 + ntg * 2 + g2) * 66 + 1 + gy) * 68 + 1 + gx) * 8] = v;
  }
  if (tid < 16) {
    float tot = redm[0][tid] + redm[1][tid];
    atomicAdd(&avg[b * 64 + ntg * 16 + tid], tot * (1.f / 4096.f));
  }
}

// ---------------------------------------------------------------------------
// enccarafe: fused gate + edge + enc MFMA + softmax + carafe (fdot2).
// Tile 8 wide x 2 high. Grid (8,32,2): z = b -> 512 blocks = 2 blocks/CU.
// 512 thr. LDS ~38KB. R14: wave-parallel gate matvec; 2-chain enc MFMA.
// ---------------------------------------------------------------------------
#define SM_XT  0       // 16*624 f16 = 19968 B  [gg][6r][13c][8]
#define SM_XSV 19968   // 8*328 f16 = 5248 B    [gg][4r][10c][8]
#define SM_TS  25216   // 8*584 f16 = 9344 B    [gg][6r][12c][8] (alias sml)
#define SM_SML 25216   // 16*116 f32 = 7424 B
#define SM_SMW 32640   // 15*16*4 f16x2 = 3840 B
#define SM_WED 36480   // 72 f16x8 = 1152 B
#define SM_TLA 37632   // 8 f32
#define SM_GSH 37664   // 64 f32
#define SM_TOT 37920

__global__ __launch_bounds__(512) void enccarafe_kernel(
    const _Float16* __restrict__ wfeatp, const f16x8* __restrict__ wfe,
    const _Float16* __restrict__ xpad8, const f16x8* __restrict__ wedgeT,
    const float* __restrict__ wa1, const float* __restrict__ ba1,
    const float* __restrict__ wa2, const float* __restrict__ ba2,
    const float* __restrict__ avg, float* __restrict__ out) {
  __shared__ __attribute__((aligned(16))) char smem[SM_TOT];
  _Float16* xt = (_Float16*)(smem + SM_XT);
  _Float16* xsv = (_Float16*)(smem + SM_XSV);
  _Float16* ts = (_Float16*)(smem + SM_TS);
  float* sml = (float*)(smem + SM_SML);
  f16x2* smw2 = (f16x2*)(smem + SM_SMW);
  f16x8* wedt = (f16x8*)(smem + SM_WED);
  float* tlat = (float*)(smem + SM_TLA);
  float* gsh = (float*)(smem + SM_GSH);

  const int tid = threadIdx.x;
  const int b = blockIdx.z;
  const int tx0 = blockIdx.x * 8, ty0 = blockIdx.y * 2;

  // --- stage X tile (16gg x 6r x 13c), W halo (8gg x 6r x 12c), misc ---
  for (int u = tid; u < 1248; u += 512) {
    int gg = u / 78;
    int rem = u - gg * 78;
    int r = rem / 13, c = rem - r * 13;
    f16x8 v = *(const f16x8*)&xpad8[((size_t)((b * 16 + gg) * 68 + ty0 + r) * 72 + tx0 + c) * 8];
    *(f16x8*)&xt[gg * 624 + r * 104 + c * 8] = v;
  }
  for (int u = tid; u < 576; u += 512) {
    int gg = u / 72;
    int rem = u - gg * 72;
    int r = rem / 12, c = rem - r * 12;
    int pr = ty0 - 1 + r, pc = tx0 - 1 + c;
    f16x8 v = {(_Float16)0.f, (_Float16)0.f, (_Float16)0.f, (_Float16)0.f,
               (_Float16)0.f, (_Float16)0.f, (_Float16)0.f, (_Float16)0.f};
    if (pr >= 0 && pr < 66 && pc >= 0 && pc < 68)
      v = *(const f16x8*)&wfeatp[((size_t)((b * 8 + gg) * 66 + pr) * 68 + pc) * 8];
    *(f16x8*)&ts[gg * 584 + r * 96 + c * 8] = v;
  }
  if (tid < 72) wedt[tid] = wedgeT[tid];
  // wave-parallel gate matvec layer 1: 64 thr = 8 out x 8 partials
  if (tid < 64) {
    int o = tid >> 3, part = tid & 7;
    const float* wr = wa1 + o * 64 + part * 8;
    const float* av = avg + b * 64 + part * 8;
    float s = 0.f;
#pragma unroll
    for (int i = 0; i < 8; ++i) s += wr[i] * av[i];
    s += __shfl_down(s, 4);
    s += __shfl_down(s, 2);
    s += __shfl_down(s, 1);
    if (part == 0) tlat[o] = s + ba1[o];
  }
  __syncthreads();
  if (tid < 64) {
    float s = ba2[tid];
#pragma unroll
    for (int j = 0; j < 8; ++j) s += wa2[tid * 8 + j] * tlat[j];
    gsh[tid] = 1.f / (1.f + expf(-s));
  }
  __syncthreads();

  // --- edge: V = W*gate + depthwise3x3(W), into xsv (8gg x 4r x 10c) ---
  if (tid < 320) {
    int gg = tid / 40;
    int rem = tid - gg * 40;
    int r6 = rem / 10, c10 = rem - r6 * 10;
    int vy = ty0 - 1 + r6, vx = tx0 - 1 + c10;
    f16x8 res = {(_Float16)0.f, (_Float16)0.f, (_Float16)0.f, (_Float16)0.f,
                 (_Float16)0.f, (_Float16)0.f, (_Float16)0.f, (_Float16)0.f};
    if (vy >= 0 && vy < 64 && vx >= 0 && vx < 64) {
      float vout[8];
      f16x8 ctr = *(const f16x8*)&ts[gg * 584 + (r6 + 1) * 96 + (c10 + 1) * 8];
#pragma unroll
      for (int j = 0; j < 8; ++j) vout[j] = (float)ctr[j] * gsh[gg * 8 + j];
#pragma unroll
      for (int ky = 0; ky < 3; ++ky) {
#pragma unroll
        for (int kx = 0; kx < 3; ++kx) {
          int k = ky * 3 + kx;
          f16x8 tv = *(const f16x8*)&ts[gg * 584 + (r6 + ky) * 96 + (c10 + kx) * 8];
          f16x8 wv = wedt[k * 8 + gg];
#pragma unroll
          for (int j = 0; j < 8; ++j) vout[j] = fmaf((float)wv[j], (float)tv[j], vout[j]);
        }
      }
#pragma unroll
      for (int j = 0; j < 8; ++j) res[j] = (_Float16)vout[j];
    }
    *(f16x8*)&xsv[gg * 328 + r6 * 80 + c10 * 8] = res;
  }
  __syncthreads();

  // --- enc MFMA: V (4x10 halo) -> 112 logits per pixel, 2 chains per wave ---
  {
    const int w = __builtin_amdgcn_readfirstlane(tid >> 6);
    const int l = tid & 63;
    if (w < 7) {
      const int nt = w;
      const int lm = l & 15, lg = l >> 4;
      const int abase = (lm >> 3) * 80 + (lm & 7) * 8;

      f32x4 a0 = {0.f, 0.f, 0.f, 0.f}, a1 = {0.f, 0.f, 0.f, 0.f};
      for (int dy = 0; dy < 3; ++dy) {
        for (int dx = 0; dx < 3; ++dx) {
          const int t = dy * 3 + dx;
          const int toff = abase + dy * 80 + dx * 8;
          {
            f16x8 a = *(const f16x8*)&xsv[(0 * 4 + lg) * 328 + toff];
            f16x8 b0 = wfe[((t * 2 + 0) * 7 + nt) * 64 + l];
            a0 = __builtin_amdgcn_mfma_f32_16x16x32_f16(a, b0, a0, 0, 0, 0);
          }
          {
            f16x8 a = *(const f16x8*)&xsv[(1 * 4 + lg) * 328 + toff];
            f16x8 b1 = wfe[((t * 2 + 1) * 7 + nt) * 64 + l];
            a1 = __builtin_amdgcn_mfma_f32_16x16x32_f16(a, b1, a1, 0, 0, 0);
          }
        }
      }
#pragma unroll
      for (int r = 0; r < 4; ++r)
        sml[(4 * lg + r) * 116 + nt * 16 + lm] = a0[r] + a1[r];
    }
  }
  __syncthreads();

  // --- softmax over 25 taps x 4 subpix -> paired f16x2 weights ---
  if (tid < 64) {
    int pix = tid >> 2, sub = tid & 3;
    float lv[25];
    float m = -1e30f;
#pragma unroll
    for (int k = 0; k < 25; ++k) {
      lv[k] = sml[pix * 116 + k * 4 + sub];
      m = fmaxf(m, lv[k]);
    }
    float s = 0.f;
#pragma unroll
    for (int k = 0; k < 25; ++k) {
      lv[k] = __expf(lv[k] - m);
      s += lv[k];
    }
    float inv = 1.f / s;
#pragma unroll
    for (int ki = 0; ki < 5; ++ki) {
#pragma unroll
      for (int pr = 0; pr < 3; ++pr) {
        float wlo = lv[ki * 5 + 2 * pr] * inv;
        float whi = (2 * pr + 1 < 5) ? lv[ki * 5 + 2 * pr + 1] * inv : 0.f;
        f16x2 pk = {(_Float16)wlo, (_Float16)whi};
        smw2[((ki * 3 + pr) * 16 + pix) * 4 + sub] = pk;
      }
    }
  }
  __syncthreads();

  // --- carafe gather via fdot2: 512 thr = 16 slot(8ch) x 2 sy x 16 pix ---
  {
    const int slot = tid >> 5;
    const int rem = tid & 31;
    const int syh = rem >> 4, pix = rem & 15;
    const int py = pix >> 3, px = pix & 7;
    const _Float16* xb = xt + slot * 624;

    float acc[2][8];
#pragma unroll
    for (int s = 0; s < 2; ++s)
#pragma unroll
      for (int j = 0; j < 8; ++j) acc[s][j] = 0.f;

    union U8 { f16x8 v; unsigned int u[4]; };
#pragma unroll
    for (int ki = 0; ki < 5; ++ki) {
      const _Float16* row = xb + (py + ki) * 104 + px * 8;
      U8 C[6];
#pragma unroll
      for (int c = 0; c < 6; ++c) C[c].v = *(const f16x8*)(row + c * 8);
#pragma unroll
      for (int pr = 0; pr < 3; ++pr) {
        const f16x2* wp = &smw2[((ki * 3 + pr) * 16 + pix) * 4 + syh * 2];
        f16x2 w0 = wp[0], w1 = wp[1];
        const U8& A = C[2 * pr];
        const U8& B = C[2 * pr + 1];
#pragma unroll
        for (int k = 0; k < 4; ++k) {
          unsigned int lo = __builtin_amdgcn_perm(B.u[k], A.u[k], 0x05040100u);
          unsigned int hi = __builtin_amdgcn_perm(B.u[k], A.u[k], 0x07060302u);
          f16x2 xlo = __builtin_bit_cast(f16x2, lo);
          f16x2 xhi = __builtin_bit_cast(f16x2, hi);
          acc[0][2 * k] = FDOT2(w0, xlo, acc[0][2 * k]);
          acc[1][2 * k] = FDOT2(w1, xlo, acc[1][2 * k]);
          acc[0][2 * k + 1] = FDOT2(w0, xhi, acc[0][2 * k + 1]);
          acc[1][2 * k + 1] = FDOT2(w1, xhi, acc[1][2 * k + 1]);
        }
      }
    }
    int y0o = 2 * (ty0 + py) + syh, x0o = 2 * (tx0 + px);
#pragma unroll
    for (int j = 0; j < 8; ++j) {
      int c = slot * 8 + j;
      float* op = out + ((size_t)(b * 128 + c) * 128 + y0o) * 128 + x0o;
      float2 v0 = {acc[0][j], acc[1][j]};
      *(float2*)op = v0;
    }
  }
}

// ---------------------------------------------------------------------------
extern "C" void kernel_launch(void* const* d_in, const int* in_sizes, int n_in,
                              void* d_out, int out_size, void* d_ws, size_t ws_size,
                              hipStream_t stream) {
  const float* X     = (const float*)d_in[0];
  const float* w3    = (const float*)d_in[1];
  const float* b3    = (const float*)d_in[2];
  const float* w5    = (const float*)d_in[3];
  const float* b5    = (const float*)d_in[4];
  const float* wa1   = (const float*)d_in[5];
  const float* ba1   = (const float*)d_in[6];
  const float* wa2   = (const float*)d_in[7];
  const float* ba2   = (const float*)d_in[8];
  const float* wedge = (const float*)d_in[9];
  const float* wenc  = (const float*)d_in[10];
  char* wsb = (char*)d_ws;  // ~4.2 MB
  float* out = (float*)d_out;

  _Float16* xpad8  = (_Float16*)(wsb + XPAD8_B);
  f16x8*    wfc    = (f16x8*)(wsb + WFC_B);
  f16x8*    wfe    = (f16x8*)(wsb + WFE_B);
  _Float16* wfeatp = (_Float16*)(wsb + WFEATP_B);
  f16x8*    wedgeT = (f16x8*)(wsb + WEDGET_B);
  float*    bcomb  = (float*)(wsb + BCOMB_B);
  float*    avg    = (float*)(wsb + AVG_B);

  prep_kernel<<<612, 256, 0, stream>>>(X, w3, b3, w5, b5, wedge, wenc, wsb);
  convw_kernel<<<dim3(8, 16, 8), 256, 0, stream>>>(xpad8, wfc, bcomb, wfeatp, avg);
  enccarafe_kernel<<<dim3(8, 32, 2), 512, 0, stream>>>(
      wfeatp, wfe, xpad8, wedgeT, wa1, ba1, wa2, ba2, avg, out);
}

// Round 15
// 40.995 us; speedup vs baseline: 4.0365x; 1.0051x over previous
//
#include <hip/hip_runtime.h>
#include <math.h>

typedef __attribute__((ext_vector_type(2))) _Float16 f16x2;
typedef __attribute__((ext_vector_type(4))) _Float16 f16x4;
typedef __attribute__((ext_vector_type(8))) _Float16 f16x8;
typedef __attribute__((ext_vector_type(4))) float f32x4;

#if __has_builtin(__builtin_amdgcn_fdot2)
#define FDOT2(a, b, c) __builtin_amdgcn_fdot2((a), (b), (c), false)
#else
static __device__ __forceinline__ float FDOT2(f16x2 a, f16x2 b, float c) {
  return c + (float)a[0] * (float)b[0] + (float)a[1] * (float)b[1];
}
#endif

// Workspace byte offsets
#define XPAD8_B  0           // [2][16 gg][68 y][72 x][8 ci] f16 (data at y+2,x+2)
#define WFC_B    2506752     // convw B-frags [25 t][4 cc][4 ntg][64 l] f16x8
#define WFE_B    2916352     // enc  B-frags [9 t][2 cc][7 nt][64 l] f16x8
#define WFEATP_B 3045376     // [2][8 gg][66][68][8] f16 pre-edge W (data at +1,+1)
#define WEDGET_B 4194304     // [9 k][8 gg] f16x8 (j fastest) depthwise weights
#define BCOMB_B  4195456     // [64] f32
#define AVG_B    4195712     // [128] f32 (seeded with bias)
// total ~4.2 MB

// ---------------------------------------------------------------------------
// prep: Xpad8, MFMA B-frag packs (K=32), wfeatp border zeros, wedgeT, bias.
// ---------------------------------------------------------------------------
__global__ __launch_bounds__(256) void prep_kernel(
    const float* __restrict__ X,
    const float* __restrict__ w3, const float* __restrict__ b3,
    const float* __restrict__ w5, const float* __restrict__ b5,
    const float* __restrict__ wedge, const float* __restrict__ wenc,
    char* __restrict__ wsb) {
  int idx = blockIdx.x * 256 + threadIdx.x;
  if (idx < 156672) {  // Xpad8
    int x = idx % 72;
    int t = idx / 72;
    int y = t % 68;
    int t2 = t / 68;
    int gg = t2 & 15, b = t2 >> 4;
    int yy = y - 2, xx = x - 2;
    bool ok = (yy >= 0 && yy < 64 && xx >= 0 && xx < 64);
    f16x8 h;
#pragma unroll
    for (int j = 0; j < 8; ++j) {
      float v = ok ? X[((b * 128 + gg * 8 + j) << 12) + yy * 64 + xx] : 0.f;
      h[j] = (_Float16)v;
    }
    ((f16x8*)(wsb + XPAD8_B))[idx] = h;
  }
  if (idx < 25600) {  // convw frags: ((t*4+cc)*4+ntg)*64 + l
    int l = idx & 63;
    int q = idx >> 6;
    int ntg = q & 3;
    int q2 = q >> 2;
    int cc = q2 & 3;
    int t = q2 >> 2;
    int ky = t / 5, kx = t % 5;
    int oc = ntg * 16 + (l & 15);
    int ci0 = cc * 32 + (l >> 4) * 8;
    f16x8 h;
#pragma unroll
    for (int i = 0; i < 8; ++i) {
      int ci = ci0 + i;
      float v = w5[(oc * 128 + ci) * 25 + t];
      if (ky >= 1 && ky <= 3 && kx >= 1 && kx <= 3)
        v += w3[(oc * 128 + ci) * 9 + (ky - 1) * 3 + (kx - 1)];
      h[i] = (_Float16)v;
    }
    ((f16x8*)(wsb + WFC_B))[idx] = h;
  }
  if (idx < 8064) {  // enc frags: ((t*2+cc)*7+nt)*64 + l
    int l = idx & 63;
    int q = idx >> 6;
    int nt = q % 7;
    int q2 = q / 7;
    int cc = q2 & 1;
    int t = q2 >> 1;
    int oc = nt * 16 + (l & 15);
    int ci0 = cc * 32 + (l >> 4) * 8;
    f16x8 h;
#pragma unroll
    for (int i = 0; i < 8; ++i) {
      float v = (oc < 100) ? wenc[(oc * 64 + ci0 + i) * 9 + t] : 0.f;
      h[i] = (_Float16)v;
    }
    ((f16x8*)(wsb + WFE_B))[idx] = h;
  }
  if (idx < 6272) {  // wfeatp border zeros: 16 planes x 392 positions
    int plane = idx / 392, p = idx % 392;
    int r, c;
    if (p < 136) {
      r = (p >= 68) ? 65 : 0;
      c = p % 68;
    } else {
      int q = p - 136;
      r = 1 + (q >> 2);
      int cm = q & 3;
      c = (cm == 0) ? 0 : (64 + cm);
    }
    f16x8 z = {(_Float16)0.f, (_Float16)0.f, (_Float16)0.f, (_Float16)0.f,
               (_Float16)0.f, (_Float16)0.f, (_Float16)0.f, (_Float16)0.f};
    *(f16x8*)((_Float16*)(wsb + WFEATP_B) + ((size_t)(plane * 66 + r) * 68 + c) * 8) = z;
  }
  if (idx < 72) {  // wedgeT [k][gg] f16x8 over j
    int k = idx >> 3, gg = idx & 7;
    f16x8 h;
#pragma unroll
    for (int j = 0; j < 8; ++j) h[j] = (_Float16)wedge[(gg * 8 + j) * 9 + k];
    ((f16x8*)(wsb + WEDGET_B))[idx] = h;
  }
  if (idx < 64) ((float*)(wsb + BCOMB_B))[idx] = b3[idx] + b5[idx];
  if (idx < 128) ((float*)(wsb + AVG_B))[idx] = b3[idx & 63] + b5[idx & 63];
}

// ---------------------------------------------------------------------------
// convw: 5x5 conv, mfma 16x16x32, fused mean. Tile 8x4 px, 16 oc.
// Grid (8,16,8): z = b*4 + ntg -> 1024 blocks = 4 blocks/CU, 16 waves/CU.
// 256 thr = 4 waves: (pg = w&1 pixel 16-group, kh = w>>1 K-half).
// 2 independent MFMA chains per wave (cc2 parity). (R14 best)
// ---------------------------------------------------------------------------
__global__ __launch_bounds__(256) void convw_kernel(
    const _Float16* __restrict__ xpad8, const f16x8* __restrict__ wfc,
    const float* __restrict__ bcomb, _Float16* __restrict__ wfeatp,
    float* __restrict__ avg) {
  __shared__ __attribute__((aligned(16))) _Float16 xs[16 * 776];
  __shared__ float red[2][64][4];
  __shared__ float redm[2][16];
  const int tid = threadIdx.x;
  const int z = blockIdx.z;
  const int b = z >> 2, ntg = z & 3;
  const int tx0 = blockIdx.x * 8, ty0 = blockIdx.y * 4;

  for (int u = tid; u < 1536; u += 256) {
    int gg = u / 96;
    int rem = u - gg * 96;
    int r = rem / 12, c = rem - r * 12;
    f16x8 v = *(const f16x8*)&xpad8[((size_t)((b * 16 + gg) * 68 + ty0 + r) * 72 + tx0 + c) * 8];
    *(f16x8*)&xs[gg * 776 + r * 96 + c * 8] = v;
  }
  __syncthreads();

  const int w = __builtin_amdgcn_readfirstlane(tid >> 6);
  const int l = tid & 63;
  const int pg = w & 1, kh = w >> 1;
  const int lm = l & 15, lg = l >> 4;
  const int p = pg * 16 + lm;
  const int abase = (p >> 3) * 96 + (p & 7) * 8;

  f32x4 acc0 = {0.f, 0.f, 0.f, 0.f}, acc1 = {0.f, 0.f, 0.f, 0.f};
  for (int dy = 0; dy < 5; ++dy) {
    for (int dx = 0; dx < 5; ++dx) {
      const int t = dy * 5 + dx;
      const int toff = abase + dy * 96 + dx * 8;
      {
        const int cc = kh * 2;
        f16x8 a = *(const f16x8*)&xs[(cc * 4 + lg) * 776 + toff];
        f16x8 bb = wfc[((t * 4 + cc) * 4 + ntg) * 64 + l];
        acc0 = __builtin_amdgcn_mfma_f32_16x16x32_f16(a, bb, acc0, 0, 0, 0);
      }
      {
        const int cc = kh * 2 + 1;
        f16x8 a = *(const f16x8*)&xs[(cc * 4 + lg) * 776 + toff];
        f16x8 bb = wfc[((t * 4 + cc) * 4 + ntg) * 64 + l];
        acc1 = __builtin_amdgcn_mfma_f32_16x16x32_f16(a, bb, acc1, 0, 0, 0);
      }
    }
  }
  f32x4 acc = acc0 + acc1;

  if (kh == 1) {
#pragma unroll
    for (int r = 0; r < 4; ++r) red[pg][l][r] = acc[r];
  }
  __syncthreads();
  if (kh == 0) {
#pragma unroll
    for (int r = 0; r < 4; ++r) acc[r] += red[pg][l][r];
    float s = acc[0] + acc[1] + acc[2] + acc[3];
    s += __shfl_xor(s, 16);
    s += __shfl_xor(s, 32);
    if (lg == 0) redm[pg][lm] = s;
    const float bias = bcomb[ntg * 16 + lm];
#pragma unroll
    for (int r = 0; r < 4; ++r) {
      int pd = pg * 16 + lg * 4 + r;
      xs[pd * 24 + lm] = (_Float16)(acc[r] + bias);
    }
  }
  __syncthreads();
  if (tid < 64) {
    int pd = tid >> 1, g2 = tid & 1;
    f16x8 v = *(const f16x8*)&xs[pd * 24 + g2 * 8];
    int gy = ty0 + (pd >> 3), gx = tx0 + (pd & 7);
    *(f16x8*)&wfeatp[((size_t)((b * 8 + ntg * 2 + g2) * 66 + 1 + gy) * 68 + 1 + gx) * 8] = v;
  }
  if (tid < 16) {
    float tot = redm[0][tid] + redm[1][tid];
    atomicAdd(&avg[b * 64 + ntg * 16 + tid], tot * (1.f / 4096.f));
  }
}

// ---------------------------------------------------------------------------
// enccarafe: fused gate + edge + enc MFMA + softmax + carafe (fdot2).
// Tile 8 wide x 2 high. Grid (8,32,2): z = b -> 512 blocks = 2 blocks/CU.
// 512 thr. LDS ~38KB. R15: T14 async-STAGE split for the xt X-tile —
// issue global loads into registers early, commit to LDS after edge.
// ---------------------------------------------------------------------------
#define SM_XT  0       // 16*624 f16 = 19968 B  [gg][6r][13c][8]
#define SM_XSV 19968   // 8*328 f16 = 5248 B    [gg][4r][10c][8]
#define SM_TS  25216   // 8*584 f16 = 9344 B    [gg][6r][12c][8] (alias sml)
#define SM_SML 25216   // 16*116 f32 = 7424 B
#define SM_SMW 32640   // 15*16*4 f16x2 = 3840 B
#define SM_WED 36480   // 72 f16x8 = 1152 B
#define SM_TLA 37632   // 8 f32
#define SM_GSH 37664   // 64 f32
#define SM_TOT 37920

__global__ __launch_bounds__(512) void enccarafe_kernel(
    const _Float16* __restrict__ wfeatp, const f16x8* __restrict__ wfe,
    const _Float16* __restrict__ xpad8, const f16x8* __restrict__ wedgeT,
    const float* __restrict__ wa1, const float* __restrict__ ba1,
    const float* __restrict__ wa2, const float* __restrict__ ba2,
    const float* __restrict__ avg, float* __restrict__ out) {
  __shared__ __attribute__((aligned(16))) char smem[SM_TOT];
  _Float16* xt = (_Float16*)(smem + SM_XT);
  _Float16* xsv = (_Float16*)(smem + SM_XSV);
  _Float16* ts = (_Float16*)(smem + SM_TS);
  float* sml = (float*)(smem + SM_SML);
  f16x2* smw2 = (f16x2*)(smem + SM_SMW);
  f16x8* wedt = (f16x8*)(smem + SM_WED);
  float* tlat = (float*)(smem + SM_TLA);
  float* gsh = (float*)(smem + SM_GSH);

  const int tid = threadIdx.x;
  const int b = blockIdx.z;
  const int tx0 = blockIdx.x * 8, ty0 = blockIdx.y * 2;

  // --- stage W halo ts (loads + immediate LDS writes) ---
  for (int u = tid; u < 576; u += 512) {
    int gg = u / 72;
    int rem = u - gg * 72;
    int r = rem / 12, c = rem - r * 12;
    int pr = ty0 - 1 + r, pc = tx0 - 1 + c;
    f16x8 v = {(_Float16)0.f, (_Float16)0.f, (_Float16)0.f, (_Float16)0.f,
               (_Float16)0.f, (_Float16)0.f, (_Float16)0.f, (_Float16)0.f};
    if (pr >= 0 && pr < 66 && pc >= 0 && pc < 68)
      v = *(const f16x8*)&wfeatp[((size_t)((b * 8 + gg) * 66 + pr) * 68 + pc) * 8];
    *(f16x8*)&ts[gg * 584 + r * 96 + c * 8] = v;
  }
  // --- T14: issue xt global loads into registers (commit after edge) ---
  const int xu0 = tid, xu1 = tid + 512, xu2 = tid + 1024;
  const bool has2 = (xu2 < 1248);
  f16x8 xr0, xr1, xr2;
  {
    int gg = xu0 / 78, rem = xu0 - (xu0 / 78) * 78, r = rem / 13, c = rem - (rem / 13) * 13;
    xr0 = *(const f16x8*)&xpad8[((size_t)((b * 16 + gg) * 68 + ty0 + r) * 72 + tx0 + c) * 8];
  }
  {
    int gg = xu1 / 78, rem = xu1 - (xu1 / 78) * 78, r = rem / 13, c = rem - (rem / 13) * 13;
    xr1 = *(const f16x8*)&xpad8[((size_t)((b * 16 + gg) * 68 + ty0 + r) * 72 + tx0 + c) * 8];
  }
  if (has2) {
    int gg = xu2 / 78, rem = xu2 - (xu2 / 78) * 78, r = rem / 13, c = rem - (rem / 13) * 13;
    xr2 = *(const f16x8*)&xpad8[((size_t)((b * 16 + gg) * 68 + ty0 + r) * 72 + tx0 + c) * 8];
  }

  if (tid < 72) wedt[tid] = wedgeT[tid];
  // wave-parallel gate matvec layer 1: 64 thr = 8 out x 8 partials
  if (tid < 64) {
    int o = tid >> 3, part = tid & 7;
    const float* wr = wa1 + o * 64 + part * 8;
    const float* av = avg + b * 64 + part * 8;
    float s = 0.f;
#pragma unroll
    for (int i = 0; i < 8; ++i) s += wr[i] * av[i];
    s += __shfl_down(s, 4);
    s += __shfl_down(s, 2);
    s += __shfl_down(s, 1);
    if (part == 0) tlat[o] = s + ba1[o];
  }
  __syncthreads();
  if (tid < 64) {
    float s = ba2[tid];
#pragma unroll
    for (int j = 0; j < 8; ++j) s += wa2[tid * 8 + j] * tlat[j];
    gsh[tid] = 1.f / (1.f + expf(-s));
  }
  __syncthreads();

  // --- edge: V = W*gate + depthwise3x3(W), into xsv (8gg x 4r x 10c) ---
  if (tid < 320) {
    int gg = tid / 40;
    int rem = tid - gg * 40;
    int r6 = rem / 10, c10 = rem - r6 * 10;
    int vy = ty0 - 1 + r6, vx = tx0 - 1 + c10;
    f16x8 res = {(_Float16)0.f, (_Float16)0.f, (_Float16)0.f, (_Float16)0.f,
                 (_Float16)0.f, (_Float16)0.f, (_Float16)0.f, (_Float16)0.f};
    if (vy >= 0 && vy < 64 && vx >= 0 && vx < 64) {
      float vout[8];
      f16x8 ctr = *(const f16x8*)&ts[gg * 584 + (r6 + 1) * 96 + (c10 + 1) * 8];
#pragma unroll
      for (int j = 0; j < 8; ++j) vout[j] = (float)ctr[j] * gsh[gg * 8 + j];
#pragma unroll
      for (int ky = 0; ky < 3; ++ky) {
#pragma unroll
        for (int kx = 0; kx < 3; ++kx) {
          int k = ky * 3 + kx;
          f16x8 tv = *(const f16x8*)&ts[gg * 584 + (r6 + ky) * 96 + (c10 + kx) * 8];
          f16x8 wv = wedt[k * 8 + gg];
#pragma unroll
          for (int j = 0; j < 8; ++j) vout[j] = fmaf((float)wv[j], (float)tv[j], vout[j]);
        }
      }
#pragma unroll
      for (int j = 0; j < 8; ++j) res[j] = (_Float16)vout[j];
    }
    *(f16x8*)&xsv[gg * 328 + r6 * 80 + c10 * 8] = res;
  }
  __syncthreads();

  // --- commit xt registers to LDS (covered by the two syncs before carafe) ---
  {
    int gg = xu0 / 78, rem = xu0 - (xu0 / 78) * 78, r = rem / 13, c = rem - (rem / 13) * 13;
    *(f16x8*)&xt[gg * 624 + r * 104 + c * 8] = xr0;
  }
  {
    int gg = xu1 / 78, rem = xu1 - (xu1 / 78) * 78, r = rem / 13, c = rem - (rem / 13) * 13;
    *(f16x8*)&xt[gg * 624 + r * 104 + c * 8] = xr1;
  }
  if (has2) {
    int gg = xu2 / 78, rem = xu2 - (xu2 / 78) * 78, r = rem / 13, c = rem - (rem / 13) * 13;
    *(f16x8*)&xt[gg * 624 + r * 104 + c * 8] = xr2;
  }

  // --- enc MFMA: V (4x10 halo) -> 112 logits per pixel, 2 chains per wave ---
  {
    const int w = __builtin_amdgcn_readfirstlane(tid >> 6);
    const int l = tid & 63;
    if (w < 7) {
      const int nt = w;
      const int lm = l & 15, lg = l >> 4;
      const int abase = (lm >> 3) * 80 + (lm & 7) * 8;

      f32x4 a0 = {0.f, 0.f, 0.f, 0.f}, a1 = {0.f, 0.f, 0.f, 0.f};
      for (int dy = 0; dy < 3; ++dy) {
        for (int dx = 0; dx < 3; ++dx) {
          const int t = dy * 3 + dx;
          const int toff = abase + dy * 80 + dx * 8;
          {
            f16x8 a = *(const f16x8*)&xsv[(0 * 4 + lg) * 328 + toff];
            f16x8 b0 = wfe[((t * 2 + 0) * 7 + nt) * 64 + l];
            a0 = __builtin_amdgcn_mfma_f32_16x16x32_f16(a, b0, a0, 0, 0, 0);
          }
          {
            f16x8 a = *(const f16x8*)&xsv[(1 * 4 + lg) * 328 + toff];
            f16x8 b1 = wfe[((t * 2 + 1) * 7 + nt) * 64 + l];
            a1 = __builtin_amdgcn_mfma_f32_16x16x32_f16(a, b1, a1, 0, 0, 0);
          }
        }
      }
#pragma unroll
      for (int r = 0; r < 4; ++r)
        sml[(4 * lg + r) * 116 + nt * 16 + lm] = a0[r] + a1[r];
    }
  }
  __syncthreads();

  // --- softmax over 25 taps x 4 subpix -> paired f16x2 weights ---
  if (tid < 64) {
    int pix = tid >> 2, sub = tid & 3;
    float lv[25];
    float m = -1e30f;
#pragma unroll
    for (int k = 0; k < 25; ++k) {
      lv[k] = sml[pix * 116 + k * 4 + sub];
      m = fmaxf(m, lv[k]);
    }
    float s = 0.f;
#pragma unroll
    for (int k = 0; k < 25; ++k) {
      lv[k] = __expf(lv[k] - m);
      s += lv[k];
    }
    float inv = 1.f / s;
#pragma unroll
    for (int ki = 0; ki < 5; ++ki) {
#pragma unroll
      for (int pr = 0; pr < 3; ++pr) {
        float wlo = lv[ki * 5 + 2 * pr] * inv;
        float whi = (2 * pr + 1 < 5) ? lv[ki * 5 + 2 * pr + 1] * inv : 0.f;
        f16x2 pk = {(_Float16)wlo, (_Float16)whi};
        smw2[((ki * 3 + pr) * 16 + pix) * 4 + sub] = pk;
      }
    }
  }
  __syncthreads();

  // --- carafe gather via fdot2: 512 thr = 16 slot(8ch) x 2 sy x 16 pix ---
  {
    const int slot = tid >> 5;
    const int rem = tid & 31;
    const int syh = rem >> 4, pix = rem & 15;
    const int py = pix >> 3, px = pix & 7;
    const _Float16* xb = xt + slot * 624;

    float acc[2][8];
#pragma unroll
    for (int s = 0; s < 2; ++s)
#pragma unroll
      for (int j = 0; j < 8; ++j) acc[s][j] = 0.f;

    union U8 { f16x8 v; unsigned int u[4]; };
#pragma unroll
    for (int ki = 0; ki < 5; ++ki) {
      const _Float16* row = xb + (py + ki) * 104 + px * 8;
      U8 C[6];
#pragma unroll
      for (int c = 0; c < 6; ++c) C[c].v = *(const f16x8*)(row + c * 8);
#pragma unroll
      for (int pr = 0; pr < 3; ++pr) {
        const f16x2* wp = &smw2[((ki * 3 + pr) * 16 + pix) * 4 + syh * 2];
        f16x2 w0 = wp[0], w1 = wp[1];
        const U8& A = C[2 * pr];
        const U8& B = C[2 * pr + 1];
#pragma unroll
        for (int k = 0; k < 4; ++k) {
          unsigned int lo = __builtin_amdgcn_perm(B.u[k], A.u[k], 0x05040100u);
          unsigned int hi = __builtin_amdgcn_perm(B.u[k], A.u[k], 0x07060302u);
          f16x2 xlo = __builtin_bit_cast(f16x2, lo);
          f16x2 xhi = __builtin_bit_cast(f16x2, hi);
          acc[0][2 * k] = FDOT2(w0, xlo, acc[0][2 * k]);
          acc[1][2 * k] = FDOT2(w1, xlo, acc[1][2 * k]);
          acc[0][2 * k + 1] = FDOT2(w0, xhi, acc[0][2 * k + 1]);
          acc[1][2 * k + 1] = FDOT2(w1, xhi, acc[1][2 * k + 1]);
        }
      }
    }
    int y0o = 2 * (ty0 + py) + syh, x0o = 2 * (tx0 + px);
#pragma unroll
    for (int j = 0; j < 8; ++j) {
      int c = slot * 8 + j;
      float* op = out + ((size_t)(b * 128 + c) * 128 + y0o) * 128 + x0o;
      float2 v0 = {acc[0][j], acc[1][j]};
      *(float2*)op = v0;
    }
  }
}

// ---------------------------------------------------------------------------
extern "C" void kernel_launch(void* const* d_in, const int* in_sizes, int n_in,
                              void* d_out, int out_size, void* d_ws, size_t ws_size,
                              hipStream_t stream) {
  const float* X     = (const float*)d_in[0];
  const float* w3    = (const float*)d_in[1];
  const float* b3    = (const float*)d_in[2];
  const float* w5    = (const float*)d_in[3];
  const float* b5    = (const float*)d_in[4];
  const float* wa1   = (const float*)d_in[5];
  const float* ba1   = (const float*)d_in[6];
  const float* wa2   = (const float*)d_in[7];
  const float* ba2   = (const float*)d_in[8];
  const float* wedge = (const float*)d_in[9];
  const float* wenc  = (const float*)d_in[10];
  char* wsb = (char*)d_ws;  // ~4.2 MB
  float* out = (float*)d_out;

  _Float16* xpad8  = (_Float16*)(wsb + XPAD8_B);
  f16x8*    wfc    = (f16x8*)(wsb + WFC_B);
  f16x8*    wfe    = (f16x8*)(wsb + WFE_B);
  _Float16* wfeatp = (_Float16*)(wsb + WFEATP_B);
  f16x8*    wedgeT = (f16x8*)(wsb + WEDGET_B);
  float*    bcomb  = (float*)(wsb + BCOMB_B);
  float*    avg    = (float*)(wsb + AVG_B);

  prep_kernel<<<612, 256, 0, stream>>>(X, w3, b3, w5, b5, wedge, wenc, wsb);
  convw_kernel<<<dim3(8, 16, 8), 256, 0, stream>>>(xpad8, wfc, bcomb, wfeatp, avg);
  enccarafe_kernel<<<dim3(8, 32, 2), 512, 0, stream>>>(
      wfeatp, wfe, xpad8, wedgeT, wa1, ba1, wa2, ba2, avg, out);
}